// Round 5
// baseline (111.994 us; speedup 1.0000x reference)
//
#include <hip/hip_runtime.h>
#include <math.h>

#define N_ATOMS 100000
#define N_EDGES 6400000
#define NZB 50000          // ceil(N_ATOMS/2) z-nibble bytes
#define TBL_BYTES (N_ATOMS * 16)           // float4 P table
#define XY_OFF    TBL_BYTES                // 1,600,000 (16B aligned)
#define Z_OFF     (XY_OFF + N_ATOMS)       // 1,700,000 (gz contiguous after gxy!)
#define WS_NEED   (Z_OFF + NZB)
#define TAB_BYTES (N_ATOMS + NZB)          // 150,000 contiguous filter-table bytes

// zbl_qz launch shape is fixed by us -> compile-time stream geometry.
#define QZ_BLOCKS  256
#define QZ_THREADS 1024
#define QZ_STRIDE  (QZ_BLOCKS * QZ_THREADS)         // 262144
#define QZ_N4      (N_EDGES / 4)                    // 1,600,000
#define QZ_ITERS   ((QZ_N4 + QZ_STRIDE - 1) / QZ_STRIDE)  // 7

// cell(x): width-6 cells over [-48,48], clamped. Cell gap >= 2 in any dim
// guarantees |delta| >= 6 -> dr >= 6 -> cos_cutoff == 0 exactly in fp32 ->
// zero contribution (validated absmax=0.0 across R4-R12). 3D pass ~10.5%.
__device__ __forceinline__ int cell6(float x) {
    return min(max((int)((x + 48.0f) * (1.0f / 6.0f)), 0), 15);
}

// Also zeroes out[0] (replaces the hipMemsetAsync graph node).
__global__ __launch_bounds__(256)
void build_tables(const float* __restrict__ R, const int* __restrict__ Z,
                  float4* __restrict__ P, unsigned char* __restrict__ gxy,
                  unsigned char* __restrict__ gz, float* __restrict__ out) {
    int i = blockIdx.x * blockDim.x + threadIdx.x;
    if (i == 0) out[0] = 0.0f;       // runs before zbl_qz in-stream
    if (i < N_ATOMS) {
        float x = R[3 * i], y = R[3 * i + 1], z = R[3 * i + 2];
        P[i] = make_float4(x, y, z, (float)Z[i]);
        gxy[i] = (unsigned char)(cell6(x) | (cell6(y) << 4));
    }
    if (i < NZB) {  // one thread per packed z-byte (2 atoms) -> no write race
        int a0 = 2 * i, a1 = 2 * i + 1;
        int c0 = cell6(R[3 * a0 + 2]);
        int c1 = (a1 < N_ATOMS) ? cell6(R[3 * a1 + 2]) : 0;
        gz[i] = (unsigned char)(c0 | (c1 << 4));
    }
}

// Shared physics body: dense drain of n queued edges (exec-masked lane<n).
__device__ __forceinline__ float zbl_body(const float4* __restrict__ P,
                                          const float* powz, uint2 e,
                                          float inv_anum,
                                          float c0, float c1, float c2, float c3,
                                          float e0, float e1, float e2, float e3) {
    const float PI_OVER_RMAX = 0.52359877559829887f;  // pi/6
    float4 pi = P[e.x];
    float4 pj = P[e.y];
    float dx = pj.x - pi.x, dy = pj.y - pi.y, dz = pj.z - pi.z;
    float d2 = dx * dx + dy * dy + dz * dz;
    if (d2 >= 36.0f) return 0.0f;          // cell test is conservative
    float dr = fmaxf(sqrtf(d2), 0.02f);    // clip [0.02, 6)
    int zi = (int)pi.w, zj = (int)pj.w;    // in [1,50)
    float dist = dr * (powz[zi & 63] + powz[zj & 63]) * inv_anum;
    float f = c0 * __expf(-e0 * dist) + c1 * __expf(-e1 * dist)
            + c2 * __expf(-e2 * dist) + c3 * __expf(-e3 * dist);
    float cc = 0.5f * (__cosf(PI_OVER_RMAX * dr) + 1.0f);
    return 0.5f * pi.w * pj.w / dr * f * cc;
}

// R13 = R12 + ALL-UPFRONT idx prefetch (7 iters x 2 int4, statically
// indexed via full unroll -> registers, rule-#20 safe). Launch shape is
// compile-time (256x1024) so ITERS=7/STRIDE=262144 are constants.
// Rationale: L3 is poisoned by the harness's 268MB fill each call, so idx
// streams from HBM (~900cyc). 2-deep covered ~2 iters; issuing all 14
// dwordx4 loads at t0 makes delivery FIFO/streaming and fully hides idx
// latency behind the 150KB LDS staging + early filter. VGPR 52->~110,
// free: occupancy is LDS-pinned (1 block/CU, 16 waves, 512 VGPR budget).
// R11 lesson kept: sz reads stay PREDICATED (xy-fail lanes broadcast
// sz[0], conflict-free); LDS conflict throughput is the scarce pipe.
__global__ __launch_bounds__(1024)
void zbl_qz(const float4* __restrict__ P,
            const unsigned char* __restrict__ gxy,   // base of 150,000B table
            const unsigned char* __restrict__ gz,    // (unused; layout contig)
            const int*    __restrict__ idx,
            const float*  __restrict__ a_exp,
            const float*  __restrict__ a_num,
            const float*  __restrict__ coef,
            const float*  __restrict__ expo,
            float*        __restrict__ out)
{
    __shared__ __align__(16) unsigned char stab[TAB_BYTES]; // sxy(100K)+sz(50K)
    __shared__ uint2 q[16 * 64];                            // 8 KB wave rings
    __shared__ float powz[64];                              // Z^a_exp LUT
    __shared__ float wave_part[16];

    const unsigned char* sxy = stab;
    const unsigned char* sz  = stab + N_ATOMS;

    const int t = threadIdx.x;
    const int tid = blockIdx.x * QZ_THREADS + t;

    const int4* idx_i4 = (const int4*)idx;              // idx[0,:]
    const int4* idx_j4 = (const int4*)(idx + N_EDGES);  // idx[1,:]

    // ---- all-upfront idx prefetch: 14 dwordx4 loads issued before staging.
    // m=6 partial: clamp OOB addresses to 0 (kv masks those lanes later).
    int4 iiA[QZ_ITERS], jjA[QZ_ITERS];
#pragma unroll
    for (int m = 0; m < QZ_ITERS; ++m) {
        int k  = tid + m * QZ_STRIDE;
        int kc = (k < QZ_N4) ? k : 0;
        iiA[m] = idx_i4[kc];
        jjA[m] = idx_j4[kc];
    }

    // single cooperative staging loop: 150,000 B = 9375 uint4 (exact)
    {
        const uint4* s = (const uint4*)gxy;   // gz == gxy + N_ATOMS in ws
        uint4*       d = (uint4*)stab;
        for (int k = t; k < TAB_BYTES / 16; k += QZ_THREADS) d[k] = s[k];
    }

    const float aexp     = a_exp[0];
    const float inv_anum = 1.0f / a_num[0];
    const float c0 = coef[0], c1 = coef[1], c2 = coef[2], c3 = coef[3];
    const float e0 = expo[0], e1 = expo[1], e2 = expo[2], e3 = expo[3];
    if (t < 64) powz[t] = __powf((float)t, aexp);  // ocml pow OK once at init
    __syncthreads();

    const int lane = t & 63;
    const int wave = t >> 6;
    uint2* myq = &q[wave << 6];          // wave-private 64-entry ring

    const unsigned long long lmask = (1ull << lane) - 1ull;

    unsigned qhead = 0, qtail = 0;   // wave-uniform (ballot-derived)
    float acc = 0.0f;

#pragma unroll
    for (int m = 0; m < QZ_ITERS; ++m) {
        const bool kv = (tid + m * QZ_STRIDE) < QZ_N4;  // partial only at m=6
        const int4 ii0 = iiA[m];
        const int4 jj0 = jjA[m];

#pragma unroll
        for (int u = 0; u < 4; ++u) {
            int i = (&ii0.x)[u];
            int j = (&jj0.x)[u];
            bool valid = kv & ((unsigned)i < N_ATOMS) & ((unsigned)j < N_ATOMS);
            unsigned a = min((unsigned)i, N_ATOMS - 1u);
            unsigned b = min((unsigned)j, N_ATOMS - 1u);
            int ci = sxy[a], cj = sxy[b];
            int dxy = abs((ci & 15) - (cj & 15)) | abs((ci >> 4) - (cj >> 4));
            bool pxy = valid & (dxy <= 1);
            // z test: reads predicated on xy pass (masked lanes -> sz[0]
            // broadcast, conflict-free -- the R11 lesson)
            unsigned aa = pxy ? (a >> 1) : 0u;
            unsigned ba = pxy ? (b >> 1) : 0u;
            int za = (sz[aa] >> ((a & 1) << 2)) & 15;
            int zb = (sz[ba] >> ((b & 1) << 2)) & 15;
            bool pass = pxy & (abs(za - zb) <= 1);

            unsigned long long mk = __ballot(pass);
            unsigned cnt   = (unsigned)__popcll(mk);
            unsigned myoff = (unsigned)__popcll(mk & lmask);

            // drain BEFORE push if the 64-entry ring would overflow
            unsigned pending = qtail - qhead;
            if (pending + cnt > 64u) {          // uniform branch
                if (lane < (int)pending) {
                    uint2 e = myq[(qhead + lane) & 63];
                    acc += zbl_body(P, powz, e, inv_anum,
                                    c0, c1, c2, c3, e0, e1, e2, e3);
                }
                qhead = qtail;                  // pending -> 0
            }
            if (pass) myq[(qtail + myoff) & 63] = make_uint2(a, b);
            qtail += cnt;
        }
    }

    // flush (pending <= 64 by construction)
    {
        unsigned pending = qtail - qhead;
        if (lane < (int)pending) {
            uint2 e = myq[(qhead + lane) & 63];
            acc += zbl_body(P, powz, e, inv_anum,
                            c0, c1, c2, c3, e0, e1, e2, e3);
        }
    }

    // wave (64-lane) shuffle reduction, then 16-wave LDS reduction
#pragma unroll
    for (int off = 32; off > 0; off >>= 1)
        acc += __shfl_down(acc, off, 64);
    if (lane == 0) wave_part[wave] = acc;
    __syncthreads();
    if (t == 0) {
        float s = 0.0f;
#pragma unroll
        for (int w = 0; w < 16; ++w) s += wave_part[w];
        atomicAdd(out, s);
    }
}

// Fallback (ws too small for tables): packed-gather MLP version with LUT.
__global__ __launch_bounds__(256)
void zbl_mlp(const float4* __restrict__ P, const int* __restrict__ idx,
             const float* __restrict__ a_exp, const float* __restrict__ a_num,
             const float* __restrict__ coef, const float* __restrict__ expo,
             float* __restrict__ out)
{
    __shared__ float powz[64];
    __shared__ float wave_part[4];
    const float aexp = a_exp[0];
    const float inv_anum = 1.0f / a_num[0];
    const float c0 = coef[0], c1 = coef[1], c2 = coef[2], c3 = coef[3];
    const float e0 = expo[0], e1 = expo[1], e2 = expo[2], e3 = expo[3];
    const int t = threadIdx.x;
    if (t < 64) powz[t] = __powf((float)t, aexp);
    __syncthreads();
    const int4* idx_i4 = (const int4*)idx;
    const int4* idx_j4 = (const int4*)(idx + N_EDGES);
    const int n4 = N_EDGES / 4;
    const int tid = blockIdx.x * blockDim.x + t;
    const int stride = gridDim.x * blockDim.x;
    const float PI_OVER_RMAX = 0.52359877559829887f;
    float acc = 0.0f;
    for (int k = tid; k < n4; k += stride) {
        int4 ii = idx_i4[k];
        int4 jj = idx_j4[k];
        float4 pa[4], pb[4];
        bool valid[4];
#pragma unroll
        for (int u = 0; u < 4; ++u) {
            int i = (&ii.x)[u], j = (&jj.x)[u];
            valid[u] = ((unsigned)i < N_ATOMS) & ((unsigned)j < N_ATOMS);
            pa[u] = P[min((unsigned)i, N_ATOMS - 1u)];
            pb[u] = P[min((unsigned)j, N_ATOMS - 1u)];
        }
#pragma unroll
        for (int u = 0; u < 4; ++u) {
            float dx = pb[u].x - pa[u].x, dy = pb[u].y - pa[u].y, dz = pb[u].z - pa[u].z;
            float d2 = dx * dx + dy * dy + dz * dz;
            if (valid[u] && d2 < 36.0f) {
                float dr = fmaxf(sqrtf(d2), 0.02f);
                int zi = (int)pa[u].w, zj = (int)pb[u].w;
                float dist = dr * (powz[zi & 63] + powz[zj & 63]) * inv_anum;
                float f = c0 * __expf(-e0 * dist) + c1 * __expf(-e1 * dist)
                        + c2 * __expf(-e2 * dist) + c3 * __expf(-e3 * dist);
                float cc = 0.5f * (__cosf(PI_OVER_RMAX * dr) + 1.0f);
                acc += 0.5f * pa[u].w * pb[u].w / dr * f * cc;
            }
        }
    }
#pragma unroll
    for (int off = 32; off > 0; off >>= 1)
        acc += __shfl_down(acc, off, 64);
    const int lane = t & 63, wave = t >> 6;
    if (lane == 0) wave_part[wave] = acc;
    __syncthreads();
    if (t == 0)
        atomicAdd(out, wave_part[0] + wave_part[1] + wave_part[2] + wave_part[3]);
}

extern "C" void kernel_launch(void* const* d_in, const int* in_sizes, int n_in,
                              void* d_out, int out_size, void* d_ws, size_t ws_size,
                              hipStream_t stream) {
    const float* R     = (const float*)d_in[0];
    const int*   Z     = (const int*)d_in[1];
    const int*   idx   = (const int*)d_in[2];
    const float* a_exp = (const float*)d_in[3];
    const float* a_num = (const float*)d_in[4];
    const float* coef  = (const float*)d_in[5];
    const float* expo  = (const float*)d_in[6];
    float* out = (float*)d_out;

    if (ws_size >= (size_t)WS_NEED) {
        float4*        P   = (float4*)d_ws;
        unsigned char* gxy = (unsigned char*)d_ws + XY_OFF;
        unsigned char* gz  = (unsigned char*)d_ws + Z_OFF;   // contiguous w/ gxy
        build_tables<<<(N_ATOMS + 255) / 256, 256, 0, stream>>>(R, Z, P, gxy, gz, out);
        // ~158.6 KB LDS -> 1 block/CU; 256 blocks x 1024 threads (QZ_* consts)
        zbl_qz<<<QZ_BLOCKS, QZ_THREADS, 0, stream>>>(P, gxy, gz, idx,
                                                     a_exp, a_num, coef, expo, out);
    } else if (ws_size >= (size_t)TBL_BYTES) {
        float4* P = (float4*)d_ws;
        build_tables<<<(N_ATOMS + 255) / 256, 256, 0, stream>>>(
            R, Z, P, (unsigned char*)d_ws, (unsigned char*)d_ws, out);  // tails unused
        zbl_mlp<<<2048, 256, 0, stream>>>(P, idx, a_exp, a_num, coef, expo, out);
    } else {
        hipMemsetAsync(out, 0, sizeof(float), stream);  // nothing else can run
    }
}

// Round 6
// 109.625 us; speedup vs baseline: 1.0216x; 1.0216x over previous
//
#include <hip/hip_runtime.h>
#include <math.h>

#define N_ATOMS 100000
#define N_EDGES 6400000
#define NZB 50000          // ceil(N_ATOMS/2) z-nibble bytes
#define TBL_BYTES (N_ATOMS * 16)           // float4 P table
#define XY_OFF    TBL_BYTES                // 1,600,000 (16B aligned)
#define Z_OFF     (XY_OFF + N_ATOMS)       // 1,700,000 (gz contiguous after gxy!)
#define WS_NEED   (Z_OFF + NZB)
#define TAB_BYTES (N_ATOMS + NZB)          // 150,000 contiguous filter-table bytes

// cell(x): width-6 cells over [-48,48], clamped. Cell gap >= 2 in any dim
// guarantees |delta| >= 6 -> dr >= 6 -> cos_cutoff == 0 exactly in fp32 ->
// zero contribution (validated absmax=0.0 across R4-R14). 3D pass ~10.5%.
__device__ __forceinline__ int cell6(float x) {
    return min(max((int)((x + 48.0f) * (1.0f / 6.0f)), 0), 15);
}

// Also zeroes out[0] (replaces the hipMemsetAsync graph node).
__global__ __launch_bounds__(256)
void build_tables(const float* __restrict__ R, const int* __restrict__ Z,
                  float4* __restrict__ P, unsigned char* __restrict__ gxy,
                  unsigned char* __restrict__ gz, float* __restrict__ out) {
    int i = blockIdx.x * blockDim.x + threadIdx.x;
    if (i == 0) out[0] = 0.0f;       // runs before zbl_qz in-stream
    if (i < N_ATOMS) {
        float x = R[3 * i], y = R[3 * i + 1], z = R[3 * i + 2];
        P[i] = make_float4(x, y, z, (float)Z[i]);
        gxy[i] = (unsigned char)(cell6(x) | (cell6(y) << 4));
    }
    if (i < NZB) {  // one thread per packed z-byte (2 atoms) -> no write race
        int a0 = 2 * i, a1 = 2 * i + 1;
        int c0 = cell6(R[3 * a0 + 2]);
        int c1 = (a1 < N_ATOMS) ? cell6(R[3 * a1 + 2]) : 0;
        gz[i] = (unsigned char)(c0 | (c1 << 4));
    }
}

// Shared physics body: dense drain of n queued edges (exec-masked lane<n).
__device__ __forceinline__ float zbl_body(const float4* __restrict__ P,
                                          const float* powz, uint2 e,
                                          float inv_anum,
                                          float c0, float c1, float c2, float c3,
                                          float e0, float e1, float e2, float e3) {
    const float PI_OVER_RMAX = 0.52359877559829887f;  // pi/6
    float4 pi = P[e.x];
    float4 pj = P[e.y];
    float dx = pj.x - pi.x, dy = pj.y - pi.y, dz = pj.z - pi.z;
    float d2 = dx * dx + dy * dy + dz * dz;
    if (d2 >= 36.0f) return 0.0f;          // cell test is conservative
    float dr = fmaxf(sqrtf(d2), 0.02f);    // clip [0.02, 6)
    int zi = (int)pi.w, zj = (int)pj.w;    // in [1,50)
    float dist = dr * (powz[zi & 63] + powz[zj & 63]) * inv_anum;
    float f = c0 * __expf(-e0 * dist) + c1 * __expf(-e1 * dist)
            + c2 * __expf(-e2 * dist) + c3 * __expf(-e3 * dist);
    float cc = 0.5f * (__cosf(PI_OVER_RMAX * dr) + 1.0f);
    return 0.5f * pi.w * pj.w / dr * f * cc;
}

// R14 = exact R12/R4 restore (best measured: 109.6us).
// Prefetch-depth study: 1-deep=110.4, 2-deep=109.6, 7-deep-upfront=112.0.
// 2-deep matches the ~900cyc HBM idx latency / ~500cyc per-iter filter
// ratio; deeper oversubscribes outstanding-VMEM and stalls issue.
// R11 lesson kept: sz reads PREDICATED on pxy (xy-fail lanes broadcast
// sz[0], conflict-free). Unpredicating costs +16us in bank conflicts --
// at 16 waves/CU, LDS latency is TLP-hidden; conflict throughput is the
// scarce pipe.
__global__ __launch_bounds__(1024)
void zbl_qz(const float4* __restrict__ P,
            const unsigned char* __restrict__ gxy,   // base of 150,000B table
            const unsigned char* __restrict__ gz,    // (unused; layout contig)
            const int*    __restrict__ idx,
            const float*  __restrict__ a_exp,
            const float*  __restrict__ a_num,
            const float*  __restrict__ coef,
            const float*  __restrict__ expo,
            float*        __restrict__ out)
{
    __shared__ __align__(16) unsigned char stab[TAB_BYTES]; // sxy(100K)+sz(50K)
    __shared__ uint2 q[16 * 64];                            // 8 KB wave rings
    __shared__ float powz[64];                              // Z^a_exp LUT
    __shared__ float wave_part[16];

    const unsigned char* sxy = stab;
    const unsigned char* sz  = stab + N_ATOMS;

    const int t = threadIdx.x;
    const int tid = blockIdx.x * blockDim.x + t;

    const int4* idx_i4 = (const int4*)idx;              // idx[0,:]
    const int4* idx_j4 = (const int4*)(idx + N_EDGES);  // idx[1,:]
    const int n4 = N_EDGES / 4;                          // 1.6M exact
    const int stride = gridDim.x * blockDim.x;           // 262144
    const int ITERS  = (n4 + stride - 1) / stride;       // 7, uniform

    // iters 0 and 1 are always fully valid (tid+stride < 2*262144 <= n4):
    // issue both quads BEFORE staging so HBM latency hides under the LDS fill.
    int4 ii0 = idx_i4[tid],          jj0 = idx_j4[tid];
    int4 ii1 = idx_i4[tid + stride], jj1 = idx_j4[tid + stride];

    // single cooperative staging loop: 150,000 B = 9375 uint4 (exact)
    {
        const uint4* s = (const uint4*)gxy;   // gz == gxy + N_ATOMS in ws
        uint4*       d = (uint4*)stab;
        for (int k = t; k < TAB_BYTES / 16; k += 1024) d[k] = s[k];
    }

    const float aexp     = a_exp[0];
    const float inv_anum = 1.0f / a_num[0];
    const float c0 = coef[0], c1 = coef[1], c2 = coef[2], c3 = coef[3];
    const float e0 = expo[0], e1 = expo[1], e2 = expo[2], e3 = expo[3];
    if (t < 64) powz[t] = __powf((float)t, aexp);  // ocml pow OK once at init
    __syncthreads();

    const int lane = t & 63;
    const int wave = t >> 6;
    uint2* myq = &q[wave << 6];          // wave-private 64-entry ring

    const unsigned long long lmask = (1ull << lane) - 1ull;

    unsigned qhead = 0, qtail = 0;   // wave-uniform (ballot-derived)
    float acc = 0.0f;

    for (int m = 0; m < ITERS; ++m) {
        // prefetch iter m+2 (clamped to edge 0 when OOB; kv masks later)
        int4 iin = make_int4(0, 0, 0, 0), jjn = make_int4(0, 0, 0, 0);
        if (m + 2 < ITERS) {
            int kn  = tid + (m + 2) * stride;
            int kcn = (kn < n4) ? kn : 0;
            iin = idx_i4[kcn];
            jjn = idx_j4[kcn];
        }
        bool kv = (tid + m * stride) < n4;   // true for m<6; partial at m=6

#pragma unroll
        for (int u = 0; u < 4; ++u) {
            int i = (&ii0.x)[u];
            int j = (&jj0.x)[u];
            bool valid = kv & ((unsigned)i < N_ATOMS) & ((unsigned)j < N_ATOMS);
            unsigned a = min((unsigned)i, N_ATOMS - 1u);
            unsigned b = min((unsigned)j, N_ATOMS - 1u);
            int ci = sxy[a], cj = sxy[b];
            int dxy = abs((ci & 15) - (cj & 15)) | abs((ci >> 4) - (cj >> 4));
            bool pxy = valid & (dxy <= 1);
            // z test: reads predicated on xy pass (masked lanes -> sz[0]
            // broadcast, conflict-free -- the R11 lesson)
            unsigned aa = pxy ? (a >> 1) : 0u;
            unsigned ba = pxy ? (b >> 1) : 0u;
            int za = (sz[aa] >> ((a & 1) << 2)) & 15;
            int zb = (sz[ba] >> ((b & 1) << 2)) & 15;
            bool pass = pxy & (abs(za - zb) <= 1);

            unsigned long long mk = __ballot(pass);
            unsigned cnt   = (unsigned)__popcll(mk);
            unsigned myoff = (unsigned)__popcll(mk & lmask);

            // drain BEFORE push if the 64-entry ring would overflow
            unsigned pending = qtail - qhead;
            if (pending + cnt > 64u) {          // uniform branch
                if (lane < (int)pending) {
                    uint2 e = myq[(qhead + lane) & 63];
                    acc += zbl_body(P, powz, e, inv_anum,
                                    c0, c1, c2, c3, e0, e1, e2, e3);
                }
                qhead = qtail;                  // pending -> 0
            }
            if (pass) myq[(qtail + myoff) & 63] = make_uint2(a, b);
            qtail += cnt;
        }

        ii0 = ii1; jj0 = jj1;      // rotate the 2-deep pipeline
        ii1 = iin; jj1 = jjn;
    }

    // flush (pending <= 64 by construction)
    {
        unsigned pending = qtail - qhead;
        if (lane < (int)pending) {
            uint2 e = myq[(qhead + lane) & 63];
            acc += zbl_body(P, powz, e, inv_anum,
                            c0, c1, c2, c3, e0, e1, e2, e3);
        }
    }

    // wave (64-lane) shuffle reduction, then 16-wave LDS reduction
#pragma unroll
    for (int off = 32; off > 0; off >>= 1)
        acc += __shfl_down(acc, off, 64);
    if (lane == 0) wave_part[wave] = acc;
    __syncthreads();
    if (t == 0) {
        float s = 0.0f;
#pragma unroll
        for (int w = 0; w < 16; ++w) s += wave_part[w];
        atomicAdd(out, s);
    }
}

// Fallback (ws too small for tables): packed-gather MLP version with LUT.
__global__ __launch_bounds__(256)
void zbl_mlp(const float4* __restrict__ P, const int* __restrict__ idx,
             const float* __restrict__ a_exp, const float* __restrict__ a_num,
             const float* __restrict__ coef, const float* __restrict__ expo,
             float* __restrict__ out)
{
    __shared__ float powz[64];
    __shared__ float wave_part[4];
    const float aexp = a_exp[0];
    const float inv_anum = 1.0f / a_num[0];
    const float c0 = coef[0], c1 = coef[1], c2 = coef[2], c3 = coef[3];
    const float e0 = expo[0], e1 = expo[1], e2 = expo[2], e3 = expo[3];
    const int t = threadIdx.x;
    if (t < 64) powz[t] = __powf((float)t, aexp);
    __syncthreads();
    const int4* idx_i4 = (const int4*)idx;
    const int4* idx_j4 = (const int4*)(idx + N_EDGES);
    const int n4 = N_EDGES / 4;
    const int tid = blockIdx.x * blockDim.x + t;
    const int stride = gridDim.x * blockDim.x;
    const float PI_OVER_RMAX = 0.52359877559829887f;
    float acc = 0.0f;
    for (int k = tid; k < n4; k += stride) {
        int4 ii = idx_i4[k];
        int4 jj = idx_j4[k];
        float4 pa[4], pb[4];
        bool valid[4];
#pragma unroll
        for (int u = 0; u < 4; ++u) {
            int i = (&ii.x)[u], j = (&jj.x)[u];
            valid[u] = ((unsigned)i < N_ATOMS) & ((unsigned)j < N_ATOMS);
            pa[u] = P[min((unsigned)i, N_ATOMS - 1u)];
            pb[u] = P[min((unsigned)j, N_ATOMS - 1u)];
        }
#pragma unroll
        for (int u = 0; u < 4; ++u) {
            float dx = pb[u].x - pa[u].x, dy = pb[u].y - pa[u].y, dz = pb[u].z - pa[u].z;
            float d2 = dx * dx + dy * dy + dz * dz;
            if (valid[u] && d2 < 36.0f) {
                float dr = fmaxf(sqrtf(d2), 0.02f);
                int zi = (int)pa[u].w, zj = (int)pb[u].w;
                float dist = dr * (powz[zi & 63] + powz[zj & 63]) * inv_anum;
                float f = c0 * __expf(-e0 * dist) + c1 * __expf(-e1 * dist)
                        + c2 * __expf(-e2 * dist) + c3 * __expf(-e3 * dist);
                float cc = 0.5f * (__cosf(PI_OVER_RMAX * dr) + 1.0f);
                acc += 0.5f * pa[u].w * pb[u].w / dr * f * cc;
            }
        }
    }
#pragma unroll
    for (int off = 32; off > 0; off >>= 1)
        acc += __shfl_down(acc, off, 64);
    const int lane = t & 63, wave = t >> 6;
    if (lane == 0) wave_part[wave] = acc;
    __syncthreads();
    if (t == 0)
        atomicAdd(out, wave_part[0] + wave_part[1] + wave_part[2] + wave_part[3]);
}

extern "C" void kernel_launch(void* const* d_in, const int* in_sizes, int n_in,
                              void* d_out, int out_size, void* d_ws, size_t ws_size,
                              hipStream_t stream) {
    const float* R     = (const float*)d_in[0];
    const int*   Z     = (const int*)d_in[1];
    const int*   idx   = (const int*)d_in[2];
    const float* a_exp = (const float*)d_in[3];
    const float* a_num = (const float*)d_in[4];
    const float* coef  = (const float*)d_in[5];
    const float* expo  = (const float*)d_in[6];
    float* out = (float*)d_out;

    if (ws_size >= (size_t)WS_NEED) {
        float4*        P   = (float4*)d_ws;
        unsigned char* gxy = (unsigned char*)d_ws + XY_OFF;
        unsigned char* gz  = (unsigned char*)d_ws + Z_OFF;   // contiguous w/ gxy
        build_tables<<<(N_ATOMS + 255) / 256, 256, 0, stream>>>(R, Z, P, gxy, gz, out);
        // ~158.6 KB LDS -> 1 block/CU; 256 blocks x 1024 threads
        zbl_qz<<<256, 1024, 0, stream>>>(P, gxy, gz, idx,
                                         a_exp, a_num, coef, expo, out);
    } else if (ws_size >= (size_t)TBL_BYTES) {
        float4* P = (float4*)d_ws;
        build_tables<<<(N_ATOMS + 255) / 256, 256, 0, stream>>>(
            R, Z, P, (unsigned char*)d_ws, (unsigned char*)d_ws, out);  // tails unused
        zbl_mlp<<<2048, 256, 0, stream>>>(P, idx, a_exp, a_num, coef, expo, out);
    } else {
        hipMemsetAsync(out, 0, sizeof(float), stream);  // nothing else can run
    }
}